// Round 5
// baseline (1601.402 us; speedup 1.0000x reference)
//
#include <hip/hip_runtime.h>
#include <hip/hip_bf16.h>

// MEASUREMENT ROUND: R2 kernels (best, 23.4us) with in-kernel rep loops
// (convert x256, gemm x128) so both dispatches exceed the ~330us harness fills
// and surface in rocprof top-5 with full counters. Final-rep output identical
// to R2 -> still passes correctness. Decomposes dur into C, G, and fixed
// graph/launch overhead Phi = 23.4 - C - G.
//
// out = value @ Wv + bv + key ;  M=2048, N=1024, K=1024

#define M_DIM 2048
#define N_DIM 1024
#define K_DIM 1024

#define REPS_CONV 256
#define REPS_GEMM 128

typedef __attribute__((ext_vector_type(8))) short short8;
typedef __attribute__((ext_vector_type(4))) float f32x4;

__device__ inline unsigned rne_bf16(float f) {
    unsigned u = __builtin_bit_cast(unsigned, f);
    return (u + 0x7FFFu + ((u >> 16) & 1u)) >> 16;
}
__device__ inline unsigned pack2(float lo, float hi) {
    return rne_bf16(lo) | (rne_bf16(hi) << 16);
}

// ---------------- K1: convert + transpose (x REPS_CONV) ----------------
__global__ __launch_bounds__(256)
void convert_kernel(const float* __restrict__ value, const float* __restrict__ Wv,
                    short* __restrict__ Vb, short* __restrict__ WvTb) {
    __shared__ unsigned tr[64 * 36];
    const int b = blockIdx.x, tid = threadIdx.x;
    #pragma unroll 1
    for (int rep = 0; rep < REPS_CONV; ++rep) {
        asm volatile("" ::: "memory");   // force re-execution each rep
        if (b < 1024) {
            int g = b * 256 + tid;
            int row = g >> 7, ch = g & 127;
            int kt = ch >> 3, c = ch & 7;
            int tm = row >> 6, r = row & 63;
            const float* p = value + (size_t)row * K_DIM + ch * 8;
            f32x4 a0 = *(const f32x4*)p;
            f32x4 a1 = *(const f32x4*)(p + 4);
            union { short8 s; unsigned u[4]; } o;
            o.u[0] = pack2(a0[0], a0[1]);
            o.u[1] = pack2(a0[2], a0[3]);
            o.u[2] = pack2(a1[0], a1[1]);
            o.u[3] = pack2(a1[2], a1[3]);
            *(short8*)&Vb[(size_t)(tm * 16 + kt) * 4096 + r * 64 + ((c ^ (r & 7)) << 3)] = o.s;
        } else {
            int b2 = b - 1024;
            int tn = b2 & 15, kt = b2 >> 4;
            #pragma unroll
            for (int s = 0; s < 2; ++s) {
                int kp = (tid >> 4) + s * 16;
                int n4 = (tid & 15) * 4;
                const float* bp = Wv + (size_t)(kt * 64 + 2 * kp) * N_DIM + tn * 64 + n4;
                f32x4 b0 = *(const f32x4*)bp;
                f32x4 b1 = *(const f32x4*)(bp + N_DIM);
                #pragma unroll
                for (int m = 0; m < 4; ++m)
                    tr[(n4 + m) * 36 + kp] = pack2(b0[m], b1[m]);
            }
            __syncthreads();
            int n = tid >> 2;
            #pragma unroll
            for (int h = 0; h < 2; ++h) {
                int c = (tid & 3) + 4 * h;
                union { short8 s; unsigned u[4]; } o;
                #pragma unroll
                for (int p = 0; p < 4; ++p)
                    o.u[p] = tr[n * 36 + c * 4 + p];
                *(short8*)&WvTb[(size_t)(tn * 16 + kt) * 4096 + n * 64 + ((c ^ (n & 7)) << 3)] = o.s;
            }
        }
        __syncthreads();   // tr reused next rep
    }
}

// ---------------- K2: bf16 GEMM (x REPS_GEMM) ----------------
__device__ inline void gl_lds16(const short* g, short* l) {
    __builtin_amdgcn_global_load_lds((const __attribute__((address_space(1))) void*)g,
                                     (__attribute__((address_space(3))) void*)l,
                                     16, 0, 0);
}

__global__ __launch_bounds__(256)
void gemm_kernel(const short* __restrict__ Vb, const short* __restrict__ WvTb,
                 const float* __restrict__ key, const float* __restrict__ bv,
                 float* __restrict__ out) {
    __shared__ __align__(16) short As[2][4096];
    __shared__ __align__(16) short Bs[2][4096];

    const int tid = threadIdx.x;
    const int bid = blockIdx.x;
    const int swz = ((bid & 7) << 6) | (bid >> 3);   // XCD swizzle (512 blocks)
    const int bm = swz >> 4;
    const int bn = swz & 15;
    const int lane = tid & 63;
    const int wid = tid >> 6;
    const int wr = wid >> 1;
    const int wc = wid & 1;

    const short* Abase = Vb + (size_t)bm * 16 * 4096;
    const short* Bbase = WvTb + (size_t)bn * 16 * 4096;
    const int row0 = bm * 64, col0 = bn * 64;
    const int colA = col0 + wc * 32 + (lane & 15);
    const int rbaseA = row0 + wr * 32 + ((lane >> 4) * 4);

    #pragma unroll 1
    for (int rep = 0; rep < REPS_GEMM; ++rep) {
        asm volatile("" ::: "memory");   // force re-execution each rep

        float keyr[2][2][4];
        float bvr[2];
        #pragma unroll
        for (int fn = 0; fn < 2; ++fn) bvr[fn] = bv[colA + fn * 16];
        #pragma unroll
        for (int fm = 0; fm < 2; ++fm)
            #pragma unroll
            for (int fn = 0; fn < 2; ++fn)
                #pragma unroll
                for (int i = 0; i < 4; ++i)
                    keyr[fm][fn][i] = key[(size_t)(rbaseA + fm * 16 + i) * N_DIM + colA + fn * 16];

        f32x4 acc[2][2] = {};

        auto stage = [&](int buf, int kt) {
            const short* ga = Abase + (size_t)kt * 4096 + tid * 8;
            const short* gb = Bbase + (size_t)kt * 4096 + tid * 8;
            gl_lds16(ga,        &As[buf][tid * 8]);
            gl_lds16(ga + 2048, &As[buf][2048 + tid * 8]);
            gl_lds16(gb,        &Bs[buf][tid * 8]);
            gl_lds16(gb + 2048, &Bs[buf][2048 + tid * 8]);
        };

        auto compute = [&](int buf) {
            #pragma unroll
            for (int ks = 0; ks < 2; ++ks) {
                short8 afr[2], bfr[2];
                const int g = ks * 4 + (lane >> 4);
                #pragma unroll
                for (int fm = 0; fm < 2; ++fm) {
                    int r = wr * 32 + fm * 16 + (lane & 15);
                    afr[fm] = *(const short8*)&As[buf][r * 64 + ((g ^ (r & 7)) << 3)];
                }
                #pragma unroll
                for (int fn = 0; fn < 2; ++fn) {
                    int n = wc * 32 + fn * 16 + (lane & 15);
                    bfr[fn] = *(const short8*)&Bs[buf][n * 64 + ((g ^ (n & 7)) << 3)];
                }
                #pragma unroll
                for (int fm = 0; fm < 2; ++fm)
                    #pragma unroll
                    for (int fn = 0; fn < 2; ++fn)
                        acc[fm][fn] = __builtin_amdgcn_mfma_f32_16x16x32_bf16(
                            afr[fm], bfr[fn], acc[fm][fn], 0, 0, 0);
            }
        };

        stage(0, 0);
        __syncthreads();
        #pragma unroll 1
        for (int kt = 0; kt < 16; ++kt) {
            if (kt < 15) stage((kt + 1) & 1, kt + 1);
            compute(kt & 1);
            __syncthreads();
        }

        #pragma unroll
        for (int fm = 0; fm < 2; ++fm) {
            #pragma unroll
            for (int fn = 0; fn < 2; ++fn) {
                int col = colA + fn * 16;
                #pragma unroll
                for (int i = 0; i < 4; ++i) {
                    int r = rbaseA + fm * 16 + i;
                    out[(size_t)r * N_DIM + col] = acc[fm][fn][i] + bvr[fn] + keyr[fm][fn][i];
                }
            }
        }
        __syncthreads();   // all waves done before next rep restages As[0]
    }
}

extern "C" void kernel_launch(void* const* d_in, const int* in_sizes, int n_in,
                              void* d_out, int out_size, void* d_ws, size_t ws_size,
                              hipStream_t stream) {
    // setup_inputs order: 0 query, 1 key, 2 value, 3 Wq, 4 bq, 5 Wk, 6 bk, 7 Wv, 8 bv, 9 U
    const float* key   = (const float*)d_in[1];
    const float* value = (const float*)d_in[2];
    const float* Wv    = (const float*)d_in[7];
    const float* bv    = (const float*)d_in[8];
    float* out = (float*)d_out;

    short* Vb   = (short*)d_ws;                         // 2048*1024 bf16 = 4 MB
    short* WvTb = (short*)d_ws + (size_t)M_DIM * K_DIM; // 1024*1024 bf16 = 2 MB

    convert_kernel<<<1024 + 256, 256, 0, stream>>>(value, Wv, Vb, WvTb);
    gemm_kernel<<<512, 256, 0, stream>>>(Vb, WvTb, key, bv, out);
}

// Round 6
// 23.741 us; speedup vs baseline: 67.4518x; 67.4518x over previous
//
#include <hip/hip_runtime.h>
#include <hip/hip_bf16.h>

// out = value @ Wv + bv + key   (softmax over [.,.,1,1] is identically 1 -> ctx == v)
// M=2048 (batch), N=1024 (d_model out), K=1024 (d_model in)
//
// K1 convert: value f32 -> Vb bf16 (tiled+swizzled); Wv f32 -> WvTb bf16 [n][k] (tiled+swizzled).
// K2 GEMM:    64x64 tiles, BK=64, global_load_lds(16B), FOUR LDS buffers,
//             lookahead-3 pipeline, counted s_waitcnt vmcnt(8) (drains 8->4->0
//             only in epilogue), ONE s_barrier per K-step, fully unrolled K-loop
//             (static buffer indices), key/bv reg-prefetch, XCD-swizzled blocks,
//             mfma_f32_16x16x32_bf16, fused bias+residual epilogue.
//
// Tile layout (Vb and WvTb): tile (t, kt) = 4096 shorts at (t*16+kt)*4096;
// element (r, kk) at r*64 + ((c ^ (r&7))<<3) + (kk&7), c = kk>>3.

#define M_DIM 2048
#define N_DIM 1024
#define K_DIM 1024

typedef __attribute__((ext_vector_type(8))) short short8;
typedef __attribute__((ext_vector_type(4))) float f32x4;

__device__ inline unsigned rne_bf16(float f) {
    unsigned u = __builtin_bit_cast(unsigned, f);
    return (u + 0x7FFFu + ((u >> 16) & 1u)) >> 16;
}
__device__ inline unsigned pack2(float lo, float hi) {
    return rne_bf16(lo) | (rne_bf16(hi) << 16);
}

// ---------------- K1: convert + transpose ----------------
__global__ __launch_bounds__(256)
void convert_kernel(const float* __restrict__ value, const float* __restrict__ Wv,
                    short* __restrict__ Vb, short* __restrict__ WvTb) {
    __shared__ unsigned tr[64 * 36];
    const int b = blockIdx.x, tid = threadIdx.x;
    if (b < 1024) {
        // value -> Vb : thread handles one 16B chunk (8 consecutive k) of one row
        int g = b * 256 + tid;
        int row = g >> 7, ch = g & 127;
        int kt = ch >> 3, c = ch & 7;
        int tm = row >> 6, r = row & 63;
        const float* p = value + (size_t)row * K_DIM + ch * 8;
        f32x4 a0 = *(const f32x4*)p;
        f32x4 a1 = *(const f32x4*)(p + 4);
        union { short8 s; unsigned u[4]; } o;
        o.u[0] = pack2(a0[0], a0[1]);
        o.u[1] = pack2(a0[2], a0[3]);
        o.u[2] = pack2(a1[0], a1[1]);
        o.u[3] = pack2(a1[2], a1[3]);
        *(short8*)&Vb[(size_t)(tm * 16 + kt) * 4096 + r * 64 + ((c ^ (r & 7)) << 3)] = o.s;
    } else {
        // Wv -> WvTb : one 64x64 tile per block, transpose via LDS (u32 = bf16 k-pair)
        int b2 = b - 1024;
        int tn = b2 & 15, kt = b2 >> 4;
        #pragma unroll
        for (int s = 0; s < 2; ++s) {
            int kp = (tid >> 4) + s * 16;           // k-pair index 0..31
            int n4 = (tid & 15) * 4;
            const float* bp = Wv + (size_t)(kt * 64 + 2 * kp) * N_DIM + tn * 64 + n4;
            f32x4 b0 = *(const f32x4*)bp;
            f32x4 b1 = *(const f32x4*)(bp + N_DIM);
            #pragma unroll
            for (int m = 0; m < 4; ++m)
                tr[(n4 + m) * 36 + kp] = pack2(b0[m], b1[m]);   // (k even, k odd)
        }
        __syncthreads();
        int n = tid >> 2;
        #pragma unroll
        for (int h = 0; h < 2; ++h) {
            int c = (tid & 3) + 4 * h;              // chunk 0..7
            union { short8 s; unsigned u[4]; } o;
            #pragma unroll
            for (int p = 0; p < 4; ++p)
                o.u[p] = tr[n * 36 + c * 4 + p];
            *(short8*)&WvTb[(size_t)(tn * 16 + kt) * 4096 + n * 64 + ((c ^ (n & 7)) << 3)] = o.s;
        }
    }
}

// ---------------- K2: bf16 GEMM, 4-buffer lookahead-3 pipeline ----------------
__device__ inline void gl_lds16(const short* g, short* l) {
    __builtin_amdgcn_global_load_lds((const __attribute__((address_space(1))) void*)g,
                                     (__attribute__((address_space(3))) void*)l,
                                     16, 0, 0);
}

__global__ __launch_bounds__(256)
void gemm_kernel(const short* __restrict__ Vb, const short* __restrict__ WvTb,
                 const float* __restrict__ key, const float* __restrict__ bv,
                 float* __restrict__ out) {
    __shared__ __align__(16) short As[4][4096];   // 32 KB
    __shared__ __align__(16) short Bs[4][4096];   // 32 KB

    const int tid = threadIdx.x;
    const int bid = blockIdx.x;
    // XCD-aware swizzle (512 blocks, 8 XCDs): each XCD gets a 4-bm x 16-bn band.
    const int swz = ((bid & 7) << 6) | (bid >> 3);
    const int bm = swz >> 4;             // 0..31
    const int bn = swz & 15;             // 0..15
    const int lane = tid & 63;
    const int wid = tid >> 6;
    const int wr = wid >> 1;             // 0..1
    const int wc = wid & 1;              // 0..1

    const short* Abase = Vb + (size_t)bm * 16 * 4096;
    const short* Bbase = WvTb + (size_t)bn * 16 * 4096;
    const int row0 = bm * 64, col0 = bn * 64;

    // ---- key/bv reg-prefetch FIRST (oldest vmem -> retires under K-loop;
    //      being oldest keeps steady-state vmcnt counts exact)
    const int colA = col0 + wc * 32 + (lane & 15);
    const int rbaseA = row0 + wr * 32 + ((lane >> 4) * 4);
    float keyr[2][2][4];
    float bvr[2];
    #pragma unroll
    for (int fn = 0; fn < 2; ++fn) bvr[fn] = bv[colA + fn * 16];
    #pragma unroll
    for (int fm = 0; fm < 2; ++fm)
        #pragma unroll
        for (int fn = 0; fn < 2; ++fn)
            #pragma unroll
            for (int i = 0; i < 4; ++i)
                keyr[fm][fn][i] = key[(size_t)(rbaseA + fm * 16 + i) * N_DIM + colA + fn * 16];

    f32x4 acc[2][2] = {};

    auto stage = [&](int buf, int kt) {
        const short* ga = Abase + (size_t)kt * 4096 + tid * 8;
        const short* gb = Bbase + (size_t)kt * 4096 + tid * 8;
        gl_lds16(ga,        &As[buf][tid * 8]);
        gl_lds16(ga + 2048, &As[buf][2048 + tid * 8]);
        gl_lds16(gb,        &Bs[buf][tid * 8]);
        gl_lds16(gb + 2048, &Bs[buf][2048 + tid * 8]);
    };

    auto compute = [&](int buf) {
        #pragma unroll
        for (int ks = 0; ks < 2; ++ks) {
            short8 afr[2], bfr[2];
            const int g = ks * 4 + (lane >> 4);
            #pragma unroll
            for (int fm = 0; fm < 2; ++fm) {
                int r = wr * 32 + fm * 16 + (lane & 15);
                afr[fm] = *(const short8*)&As[buf][r * 64 + ((g ^ (r & 7)) << 3)];
            }
            #pragma unroll
            for (int fn = 0; fn < 2; ++fn) {
                int n = wc * 32 + fn * 16 + (lane & 15);
                bfr[fn] = *(const short8*)&Bs[buf][n * 64 + ((g ^ (n & 7)) << 3)];
            }
            #pragma unroll
            for (int fm = 0; fm < 2; ++fm)
                #pragma unroll
                for (int fn = 0; fn < 2; ++fn)
                    acc[fm][fn] = __builtin_amdgcn_mfma_f32_16x16x32_bf16(
                        afr[fm], bfr[fn], acc[fm][fn], 0, 0, 0);
        }
    };

    // ---- prologue: 3 tiles in flight (12 VMEM instrs after 18 key/bv)
    stage(0, 0);
    stage(1, 1);
    stage(2, 2);

    // ---- main loop, fully unrolled (static buf indices).
    // Per step kt: wait stage(kt) landed while stage(kt+1),(kt+2) stay in flight
    // (vmcnt(8)); barrier; then issue stage(kt+3) (its LDS buffer was last read
    // by compute(kt-1), which every wave finished at this barrier); compute(kt).
    #pragma unroll
    for (int kt = 0; kt < 16; ++kt) {
        if (kt <= 13)      asm volatile("s_waitcnt vmcnt(8)" ::: "memory");
        else if (kt == 14) asm volatile("s_waitcnt vmcnt(4)" ::: "memory");
        else               asm volatile("s_waitcnt vmcnt(0)" ::: "memory");
        __builtin_amdgcn_s_barrier();
        if (kt + 3 < 16) stage((kt + 3) & 3, kt + 3);
        compute(kt & 3);
    }

    // ---- epilogue: out = acc + bv + key (all operands already in registers)
    #pragma unroll
    for (int fm = 0; fm < 2; ++fm) {
        #pragma unroll
        for (int fn = 0; fn < 2; ++fn) {
            int col = colA + fn * 16;
            #pragma unroll
            for (int i = 0; i < 4; ++i) {
                int r = rbaseA + fm * 16 + i;
                out[(size_t)r * N_DIM + col] = acc[fm][fn][i] + bvr[fn] + keyr[fm][fn][i];
            }
        }
    }
}

extern "C" void kernel_launch(void* const* d_in, const int* in_sizes, int n_in,
                              void* d_out, int out_size, void* d_ws, size_t ws_size,
                              hipStream_t stream) {
    // setup_inputs order: 0 query, 1 key, 2 value, 3 Wq, 4 bq, 5 Wk, 6 bk, 7 Wv, 8 bv, 9 U
    const float* key   = (const float*)d_in[1];
    const float* value = (const float*)d_in[2];
    const float* Wv    = (const float*)d_in[7];
    const float* bv    = (const float*)d_in[8];
    float* out = (float*)d_out;

    short* Vb   = (short*)d_ws;                         // 2048*1024 bf16 = 4 MB
    short* WvTb = (short*)d_ws + (size_t)M_DIM * K_DIM; // 1024*1024 bf16 = 2 MB

    convert_kernel<<<1024 + 256, 256, 0, stream>>>(value, Wv, Vb, WvTb);
    gemm_kernel<<<512, 256, 0, stream>>>(Vb, WvTb, key, bv, out);
}